// Round 1
// baseline (389.800 us; speedup 1.0000x reference)
//
#include <hip/hip_runtime.h>

#define S_LEN 4096
#define NH 16
#define DH 64
#define NE 1024

typedef __bf16 bf16_t;
typedef __bf16 bf16x8 __attribute__((ext_vector_type(8)));
typedef __bf16 bf16x4 __attribute__((ext_vector_type(4)));
typedef float  f32x4  __attribute__((ext_vector_type(4)));

// ---------------------------------------------------------------------------
// pack q,k into head-major bf16 (q pre-scaled by 1/sqrt(64)=0.125), W -> bf16
// qb/kb layout: [h][s][d], contiguous d. Coalesced reads and writes.
// ---------------------------------------------------------------------------
__global__ __launch_bounds__(256) void pack_qkw(const float* __restrict__ q,
                                                const float* __restrict__ k,
                                                const float* __restrict__ w,
                                                bf16_t* __restrict__ qb,
                                                bf16_t* __restrict__ kb,
                                                bf16_t* __restrict__ wb) {
    int stride = gridDim.x * blockDim.x;
    for (int idx = blockIdx.x * blockDim.x + threadIdx.x; idx < S_LEN * NE; idx += stride) {
        int s = idx >> 10;
        int c = idx & (NE - 1);
        int h = c >> 6;
        int d = c & (DH - 1);
        int o = (h * S_LEN + s) * DH + d;
        qb[o] = (bf16_t)(q[idx] * 0.125f);
        kb[o] = (bf16_t)k[idx];
        if (idx < NE * NE) wb[idx] = (bf16_t)w[idx];
    }
}

// ---------------------------------------------------------------------------
// pack V transposed: vt[h][d][t] (bf16) via LDS tile transpose.
// grid (T/64, NH), block 256.
// ---------------------------------------------------------------------------
__global__ __launch_bounds__(256) void pack_vt(const float* __restrict__ v,
                                               bf16_t* __restrict__ vt) {
    __shared__ bf16_t tile[64][65];
    const int h  = blockIdx.y;
    const int t0 = blockIdx.x * 64;
    const int r  = threadIdx.x >> 6;  // 0..3
    const int cl = threadIdx.x & 63;  // 0..63
#pragma unroll
    for (int rep = 0; rep < 16; ++rep) {
        int i = rep * 4 + r;  // t offset within tile
        tile[cl][i] = (bf16_t)v[(t0 + i) * NE + h * DH + cl];
    }
    __syncthreads();
#pragma unroll
    for (int rep = 0; rep < 16; ++rep) {
        int d = rep * 4 + r;
        vt[(h * DH + d) * S_LEN + t0 + cl] = tile[d][cl];
    }
}

// ---------------------------------------------------------------------------
// Flash attention. 1 wave = 32 q-rows (2 row-frags), K-tiles of 32 keys.
// mfma_f32_16x16x32_bf16: A[m=lane&15][k=quad*8+j], B[k=quad*8+j][n=lane&15],
// C/D[row=quad*4+reg][col=lane&15]. Online softmax in fp32.
// grid (32, 16), block 256 (4 waves, no block-level sync needed).
// ---------------------------------------------------------------------------
__global__ __launch_bounds__(256, 2) void attn(const bf16_t* __restrict__ qb,
                                               const bf16_t* __restrict__ kb,
                                               const bf16_t* __restrict__ vt,
                                               bf16_t* __restrict__ xb) {
    // per-wave P transform buffer; row stride 36 (72B) => conflict-free b16 scatter
    __shared__ bf16_t p_lds[4][2][16 * 36];
    const int wave = threadIdx.x >> 6;
    const int lane = threadIdx.x & 63;
    const int l15  = lane & 15;
    const int quad = lane >> 4;
    const int h = blockIdx.y;
    // swizzle s-tiles so per-CU causal work is balanced
    const int stile = ((blockIdx.x * 17) + blockIdx.y * 7) & 31;
    const int s0 = stile * 128 + wave * 32;

    const bf16_t* __restrict__ qh = qb + h * (S_LEN * DH);
    const bf16_t* __restrict__ kh = kb + h * (S_LEN * DH);
    const bf16_t* __restrict__ vh = vt + h * (DH * S_LEN);

    bf16x8 qA[2][2];
#pragma unroll
    for (int rf = 0; rf < 2; ++rf)
#pragma unroll
        for (int dc = 0; dc < 2; ++dc)
            qA[rf][dc] = *(const bf16x8*)(qh + (s0 + rf * 16 + l15) * DH + dc * 32 + quad * 8);

    float m_run[2][4], l_run[2][4];
    f32x4 o_acc[2][4];
#pragma unroll
    for (int rf = 0; rf < 2; ++rf) {
#pragma unroll
        for (int r = 0; r < 4; ++r) { m_run[rf][r] = -INFINITY; l_run[rf][r] = 0.0f; }
#pragma unroll
        for (int db = 0; db < 4; ++db) o_acc[rf][db] = (f32x4){0.f, 0.f, 0.f, 0.f};
    }

    for (int t0 = 0; t0 < s0 + 32; t0 += 32) {
        bf16x8 kB[2][2];
#pragma unroll
        for (int ch = 0; ch < 2; ++ch)
#pragma unroll
            for (int dc = 0; dc < 2; ++dc)
                kB[ch][dc] = *(const bf16x8*)(kh + (t0 + ch * 16 + l15) * DH + dc * 32 + quad * 8);

        bf16x8 vB[4];
#pragma unroll
        for (int db = 0; db < 4; ++db)
            vB[db] = *(const bf16x8*)(vh + (db * 16 + l15) * S_LEN + t0 + quad * 8);

        f32x4 c[2][2];
#pragma unroll
        for (int rf = 0; rf < 2; ++rf)
#pragma unroll
            for (int ch = 0; ch < 2; ++ch) {
                f32x4 z = (f32x4){0.f, 0.f, 0.f, 0.f};
                z = __builtin_amdgcn_mfma_f32_16x16x32_bf16(qA[rf][0], kB[ch][0], z, 0, 0, 0);
                z = __builtin_amdgcn_mfma_f32_16x16x32_bf16(qA[rf][1], kB[ch][1], z, 0, 0, 0);
                c[rf][ch] = z;
            }

        if (t0 + 31 > s0) {  // causal mask needed only near the diagonal
#pragma unroll
            for (int rf = 0; rf < 2; ++rf)
#pragma unroll
                for (int ch = 0; ch < 2; ++ch) {
                    int col = t0 + ch * 16 + l15;
#pragma unroll
                    for (int r = 0; r < 4; ++r) {
                        int row = s0 + rf * 16 + quad * 4 + r;
                        if (col > row) c[rf][ch][r] = -INFINITY;
                    }
                }
        }

#pragma unroll
        for (int rf = 0; rf < 2; ++rf) {
            float rmax[4], alpha[4], p0[4], p1[4], rsum[4];
#pragma unroll
            for (int r = 0; r < 4; ++r) rmax[r] = fmaxf(c[rf][0][r], c[rf][1][r]);
#pragma unroll
            for (int off = 8; off >= 1; off >>= 1)
#pragma unroll
                for (int r = 0; r < 4; ++r) rmax[r] = fmaxf(rmax[r], __shfl_xor(rmax[r], off, 64));
#pragma unroll
            for (int r = 0; r < 4; ++r) {
                float mn = fmaxf(m_run[rf][r], rmax[r]);
                alpha[r] = __expf(m_run[rf][r] - mn);   // exp(-inf)=0 on first tile
                m_run[rf][r] = mn;
                p0[r] = __expf(c[rf][0][r] - mn);
                p1[r] = __expf(c[rf][1][r] - mn);
                rsum[r] = p0[r] + p1[r];
            }
#pragma unroll
            for (int off = 8; off >= 1; off >>= 1)
#pragma unroll
                for (int r = 0; r < 4; ++r) rsum[r] += __shfl_xor(rsum[r], off, 64);
#pragma unroll
            for (int r = 0; r < 4; ++r) l_run[rf][r] = l_run[rf][r] * alpha[r] + rsum[r];
#pragma unroll
            for (int db = 0; db < 4; ++db)
#pragma unroll
                for (int r = 0; r < 4; ++r) o_acc[rf][db][r] *= alpha[r];
            // P: C-layout -> LDS (row=quad*4+r, col=lane&15 [+16])
            bf16_t* pl = p_lds[wave][rf];
#pragma unroll
            for (int r = 0; r < 4; ++r) {
                pl[(quad * 4 + r) * 36 + l15]      = (bf16_t)p0[r];
                pl[(quad * 4 + r) * 36 + 16 + l15] = (bf16_t)p1[r];
            }
        }

        __builtin_amdgcn_wave_barrier();  // keep LDS write->read order; wave-synchronous

        bf16x8 pA[2];
#pragma unroll
        for (int rf = 0; rf < 2; ++rf) {
            const bf16_t* pl = p_lds[wave][rf] + l15 * 36 + quad * 8;
            bf16x4 lo = *(const bf16x4*)(pl);
            bf16x4 hi = *(const bf16x4*)(pl + 4);
#pragma unroll
            for (int j = 0; j < 4; ++j) { pA[rf][j] = lo[j]; pA[rf][4 + j] = hi[j]; }
        }

#pragma unroll
        for (int rf = 0; rf < 2; ++rf)
#pragma unroll
            for (int db = 0; db < 4; ++db)
                o_acc[rf][db] = __builtin_amdgcn_mfma_f32_16x16x32_bf16(pA[rf], vB[db], o_acc[rf][db], 0, 0, 0);
    }

    // epilogue: normalize and store attention output as bf16, xb[s][h*64+d]
#pragma unroll
    for (int rf = 0; rf < 2; ++rf) {
        float inv[4];
#pragma unroll
        for (int r = 0; r < 4; ++r) inv[r] = 1.0f / l_run[rf][r];
#pragma unroll
        for (int db = 0; db < 4; ++db)
#pragma unroll
            for (int r = 0; r < 4; ++r) {
                int row = s0 + rf * 16 + quad * 4 + r;
                xb[row * NE + h * DH + db * 16 + l15] = (bf16_t)(o_acc[rf][db][r] * inv[r]);
            }
    }
}

// ---------------------------------------------------------------------------
// Projection: Y[4096][1024] = X(bf16) @ W^T(bf16), fp32 out.
// Both operands K-contiguous; per wave 16 rows x 64 cols.
// grid (64, 16), block 256.
// ---------------------------------------------------------------------------
__global__ __launch_bounds__(256) void proj(const bf16_t* __restrict__ xb,
                                            const bf16_t* __restrict__ wb,
                                            float* __restrict__ y) {
    const int wave = threadIdx.x >> 6;
    const int lane = threadIdx.x & 63;
    const int l15  = lane & 15;
    const int quad = lane >> 4;
    const int m0 = blockIdx.x * 64 + wave * 16;
    const int n0 = blockIdx.y * 64;

    f32x4 acc[4];
#pragma unroll
    for (int nb = 0; nb < 4; ++nb) acc[nb] = (f32x4){0.f, 0.f, 0.f, 0.f};

#pragma unroll 4
    for (int k0 = 0; k0 < NE; k0 += 32) {
        bf16x8 a = *(const bf16x8*)(xb + (m0 + l15) * NE + k0 + quad * 8);
#pragma unroll
        for (int nb = 0; nb < 4; ++nb) {
            bf16x8 b = *(const bf16x8*)(wb + (n0 + nb * 16 + l15) * NE + k0 + quad * 8);
            acc[nb] = __builtin_amdgcn_mfma_f32_16x16x32_bf16(a, b, acc[nb], 0, 0, 0);
        }
    }
#pragma unroll
    for (int nb = 0; nb < 4; ++nb)
#pragma unroll
        for (int r = 0; r < 4; ++r)
            y[(m0 + quad * 4 + r) * NE + n0 + nb * 16 + l15] = acc[nb][r];
}

extern "C" void kernel_launch(void* const* d_in, const int* in_sizes, int n_in,
                              void* d_out, int out_size, void* d_ws, size_t ws_size,
                              hipStream_t stream) {
    const float* q = (const float*)d_in[0];
    const float* k = (const float*)d_in[1];
    const float* v = (const float*)d_in[2];
    const float* w = (const float*)d_in[3];
    float* y = (float*)d_out;

    // workspace layout (bf16 elements): qb 4M | kb 4M | vt 4M | wb 1M | xb 4M = 34 MB
    bf16_t* ws = (bf16_t*)d_ws;
    bf16_t* qb = ws;
    bf16_t* kb = qb + 4 * 1024 * 1024;
    bf16_t* vt = kb + 4 * 1024 * 1024;
    bf16_t* wb = vt + 4 * 1024 * 1024;
    bf16_t* xb = wb + 1024 * 1024;

    pack_qkw<<<dim3(4096), dim3(256), 0, stream>>>(q, k, w, qb, kb, wb);
    pack_vt<<<dim3(S_LEN / 64, NH), dim3(256), 0, stream>>>(v, vt);
    attn<<<dim3(32, NH), dim3(256), 0, stream>>>(qb, kb, vt, xb);
    proj<<<dim3(S_LEN / 64, NE / 64), dim3(256), 0, stream>>>(xb, wb, y);
}

// Round 3
// 290.585 us; speedup vs baseline: 1.3414x; 1.3414x over previous
//
#include <hip/hip_runtime.h>

#define S_LEN 4096
#define NH 16
#define DH 64
#define NE 1024

typedef __bf16 bf16_t;
typedef __bf16 bf16x8 __attribute__((ext_vector_type(8)));
typedef __bf16 bf16x4 __attribute__((ext_vector_type(4)));
typedef float  f32x4  __attribute__((ext_vector_type(4)));

// ---------------------------------------------------------------------------
// pack q,k head-major bf16 (q pre-scaled 0.125), W -> bf16. float4 vectorized.
// grid 4096 x 256 = 1M threads, 1 float4 (4 elems) per thread for q/k.
// ---------------------------------------------------------------------------
__global__ __launch_bounds__(256) void pack_qkw(const float* __restrict__ q,
                                                const float* __restrict__ k,
                                                const float* __restrict__ w,
                                                bf16_t* __restrict__ qb,
                                                bf16_t* __restrict__ kb,
                                                bf16_t* __restrict__ wb) {
    const int tid = blockIdx.x * 256 + threadIdx.x;
    const int e = tid * 4;
    const int s = e >> 10;
    const int c = e & (NE - 1);
    const int h = c >> 6;
    const int d = c & (DH - 1);
    const int o = (h * S_LEN + s) * DH + d;
    float4 qv = *(const float4*)(q + e);
    float4 kv = *(const float4*)(k + e);
    bf16x4 qo, ko;
    qo[0] = (bf16_t)(qv.x * 0.125f); qo[1] = (bf16_t)(qv.y * 0.125f);
    qo[2] = (bf16_t)(qv.z * 0.125f); qo[3] = (bf16_t)(qv.w * 0.125f);
    ko[0] = (bf16_t)kv.x; ko[1] = (bf16_t)kv.y; ko[2] = (bf16_t)kv.z; ko[3] = (bf16_t)kv.w;
    *(bf16x4*)(qb + o) = qo;
    *(bf16x4*)(kb + o) = ko;
    if (tid < (NE * NE / 4)) {
        float4 wv = *(const float4*)(w + tid * 4);
        bf16x4 wo;
        wo[0] = (bf16_t)wv.x; wo[1] = (bf16_t)wv.y; wo[2] = (bf16_t)wv.z; wo[3] = (bf16_t)wv.w;
        *(bf16x4*)(wb + tid * 4) = wo;
    }
}

// ---------------------------------------------------------------------------
// pack V transposed: vt[h][d][t] (bf16) via LDS tile transpose. grid (T/64, NH).
// ---------------------------------------------------------------------------
__global__ __launch_bounds__(256) void pack_vt(const float* __restrict__ v,
                                               bf16_t* __restrict__ vt) {
    __shared__ bf16_t tile[64][65];
    const int h  = blockIdx.y;
    const int t0 = blockIdx.x * 64;
    const int r  = threadIdx.x >> 6;
    const int cl = threadIdx.x & 63;
#pragma unroll
    for (int rep = 0; rep < 16; ++rep) {
        int i = rep * 4 + r;
        tile[cl][i] = (bf16_t)v[(t0 + i) * NE + h * DH + cl];
    }
    __syncthreads();
#pragma unroll
    for (int rep = 0; rep < 16; ++rep) {
        int d = rep * 4 + r;
        vt[(h * DH + d) * S_LEN + t0 + cl] = tile[d][cl];
    }
}

// ---------------------------------------------------------------------------
// Flash attention, LDS-staged K/V, double-buffered, K-tile = 64.
// Block: 4 waves, 128 q-rows (wave w: rows base+32w..+32). grid (32, 16).
// K tile [64 key][64 d], V^T tile [64 d][64 t], P tiles [16 row][64 t]:
// ALL LDS rows stride 72 shorts (144B: 16B-aligned; frag b128 reads and b16
// scatter-writes land 2-way bank aliasing only = free per m136).
// stile pairing (h&8 ? 31-x : x): block i and i+256 (same CU under round-robin)
// get complementary diagonal work -> constant per-CU load.
// ---------------------------------------------------------------------------
__global__ __launch_bounds__(256, 2) void attn(const bf16_t* __restrict__ qb,
                                               const bf16_t* __restrict__ kb,
                                               const bf16_t* __restrict__ vt,
                                               bf16_t* __restrict__ xb) {
    __shared__ __align__(16) bf16_t kbuf[2][64 * 72];
    __shared__ __align__(16) bf16_t vbuf[2][64 * 72];
    __shared__ __align__(16) bf16_t pbuf[4][2][16 * 72];

    const int tid  = threadIdx.x;
    const int wave = tid >> 6;
    const int lane = tid & 63;
    const int l15  = lane & 15;
    const int quad = lane >> 4;
    const int h = blockIdx.y;
    const int x = blockIdx.x;
    const int stile = (h & 8) ? (31 - x) : x;
    const int base = stile * 128;
    const int s0 = base + wave * 32;

    const bf16_t* __restrict__ qh = qb + h * (S_LEN * DH);
    const bf16_t* __restrict__ kh = kb + h * (S_LEN * DH);
    const bf16_t* __restrict__ vh = vt + h * (DH * S_LEN);

    // cooperative staging map: chunk c = tid + j*256 (j=0,1); 512 chunks of 16B
    const int row0 = tid >> 3;        // j=0 row (0..31), j=1 adds 32
    const int tc8  = (tid & 7) * 8;   // column element offset (0..56)

    bf16x8 qA[2][2];
#pragma unroll
    for (int rf = 0; rf < 2; ++rf)
#pragma unroll
        for (int dc = 0; dc < 2; ++dc)
            qA[rf][dc] = *(const bf16x8*)(qh + (s0 + rf * 16 + l15) * DH + dc * 32 + quad * 8);

    float m_run[2][4], l_run[2][4];
    f32x4 o_acc[2][4];
#pragma unroll
    for (int rf = 0; rf < 2; ++rf) {
#pragma unroll
        for (int r = 0; r < 4; ++r) { m_run[rf][r] = -INFINITY; l_run[rf][r] = 0.0f; }
#pragma unroll
        for (int db = 0; db < 4; ++db) o_acc[rf][db] = (f32x4){0.f, 0.f, 0.f, 0.f};
    }

    const int ntiles = base / 64 + 2;

    // prologue: stage tile 0 into buf 0
    {
        bf16x8 kr[2], vr[2];
#pragma unroll
        for (int j = 0; j < 2; ++j) {
            int row = row0 + j * 32;
            kr[j] = *(const bf16x8*)(kh + row * DH + tc8);
            vr[j] = *(const bf16x8*)(vh + row * S_LEN + tc8);
        }
#pragma unroll
        for (int j = 0; j < 2; ++j) {
            int row = row0 + j * 32;
            *(bf16x8*)(kbuf[0] + row * 72 + tc8) = kr[j];
            *(bf16x8*)(vbuf[0] + row * 72 + tc8) = vr[j];
        }
    }
    __syncthreads();

    for (int t = 0; t < ntiles; ++t) {
        const int t0 = t * 64;
        const bf16_t* kb_ = kbuf[t & 1];
        const bf16_t* vb_ = vbuf[t & 1];

        // prefetch next tile global -> VGPRs (latency hidden by tile compute)
        bf16x8 kr[2], vr[2];
        const bool pf = (t + 1 < ntiles);
        if (pf) {
            const int t0n = t0 + 64;
#pragma unroll
            for (int j = 0; j < 2; ++j) {
                int row = row0 + j * 32;
                kr[j] = *(const bf16x8*)(kh + (t0n + row) * DH + tc8);
                vr[j] = *(const bf16x8*)(vh + row * S_LEN + t0n + tc8);
            }
        }

        // QK^T: 32 rows x 64 keys per wave
        bf16x8 kB[4][2];
#pragma unroll
        for (int ch = 0; ch < 4; ++ch)
#pragma unroll
            for (int dc = 0; dc < 2; ++dc)
                kB[ch][dc] = *(const bf16x8*)(kb_ + (ch * 16 + l15) * 72 + dc * 32 + quad * 8);

        f32x4 c_[2][4];
#pragma unroll
        for (int rf = 0; rf < 2; ++rf)
#pragma unroll
            for (int ch = 0; ch < 4; ++ch) {
                f32x4 z = (f32x4){0.f, 0.f, 0.f, 0.f};
                z = __builtin_amdgcn_mfma_f32_16x16x32_bf16(qA[rf][0], kB[ch][0], z, 0, 0, 0);
                z = __builtin_amdgcn_mfma_f32_16x16x32_bf16(qA[rf][1], kB[ch][1], z, 0, 0, 0);
                c_[rf][ch] = z;
            }

        if (t0 + 63 > s0) {  // causal mask (only tiles at/past the diagonal)
#pragma unroll
            for (int rf = 0; rf < 2; ++rf)
#pragma unroll
                for (int ch = 0; ch < 4; ++ch) {
                    int col = t0 + ch * 16 + l15;
#pragma unroll
                    for (int r = 0; r < 4; ++r) {
                        int row = s0 + rf * 16 + quad * 4 + r;
                        if (col > row) c_[rf][ch][r] = -INFINITY;
                    }
                }
        }

        // online softmax
#pragma unroll
        for (int rf = 0; rf < 2; ++rf) {
            float rmax[4], alpha[4], rsum[4], p[4][4];
#pragma unroll
            for (int r = 0; r < 4; ++r)
                rmax[r] = fmaxf(fmaxf(c_[rf][0][r], c_[rf][1][r]),
                                fmaxf(c_[rf][2][r], c_[rf][3][r]));
#pragma unroll
            for (int off = 8; off >= 1; off >>= 1)
#pragma unroll
                for (int r = 0; r < 4; ++r) rmax[r] = fmaxf(rmax[r], __shfl_xor(rmax[r], off, 64));
#pragma unroll
            for (int r = 0; r < 4; ++r) {
                float mn = fmaxf(m_run[rf][r], rmax[r]);
                alpha[r] = __expf(m_run[rf][r] - mn);  // exp(-inf)=0 on first tile
                m_run[rf][r] = mn;
                rsum[r] = 0.0f;
#pragma unroll
                for (int ch = 0; ch < 4; ++ch) {
                    p[ch][r] = __expf(c_[rf][ch][r] - mn);
                    rsum[r] += p[ch][r];
                }
            }
#pragma unroll
            for (int off = 8; off >= 1; off >>= 1)
#pragma unroll
                for (int r = 0; r < 4; ++r) rsum[r] += __shfl_xor(rsum[r], off, 64);
#pragma unroll
            for (int r = 0; r < 4; ++r) l_run[rf][r] = l_run[rf][r] * alpha[r] + rsum[r];
#pragma unroll
            for (int db = 0; db < 4; ++db)
#pragma unroll
                for (int r = 0; r < 4; ++r) o_acc[rf][db][r] *= alpha[r];
            // P: C-layout -> LDS (row = quad*4+r, col = ch*16+l15), stride 72
            bf16_t* pl = pbuf[wave][rf];
#pragma unroll
            for (int ch = 0; ch < 4; ++ch)
#pragma unroll
                for (int r = 0; r < 4; ++r)
                    pl[(quad * 4 + r) * 72 + ch * 16 + l15] = (bf16_t)p[ch][r];
        }

        __builtin_amdgcn_wave_barrier();  // per-wave LDS write->read ordering

        bf16x8 pA[2][2];
#pragma unroll
        for (int rf = 0; rf < 2; ++rf)
#pragma unroll
            for (int kc = 0; kc < 2; ++kc)
                pA[rf][kc] = *(const bf16x8*)(pbuf[wave][rf] + l15 * 72 + kc * 32 + quad * 8);

        bf16x8 vB[4][2];
#pragma unroll
        for (int db = 0; db < 4; ++db)
#pragma unroll
            for (int kc = 0; kc < 2; ++kc)
                vB[db][kc] = *(const bf16x8*)(vb_ + (db * 16 + l15) * 72 + kc * 32 + quad * 8);

#pragma unroll
        for (int rf = 0; rf < 2; ++rf)
#pragma unroll
            for (int db = 0; db < 4; ++db) {
                o_acc[rf][db] = __builtin_amdgcn_mfma_f32_16x16x32_bf16(pA[rf][0], vB[db][0], o_acc[rf][db], 0, 0, 0);
                o_acc[rf][db] = __builtin_amdgcn_mfma_f32_16x16x32_bf16(pA[rf][1], vB[db][1], o_acc[rf][db], 0, 0, 0);
            }

        // stage prefetched tile into the other buffer
        if (pf) {
            bf16_t* kd = kbuf[(t + 1) & 1];
            bf16_t* vd = vbuf[(t + 1) & 1];
#pragma unroll
            for (int j = 0; j < 2; ++j) {
                int row = row0 + j * 32;
                *(bf16x8*)(kd + row * 72 + tc8) = kr[j];
                *(bf16x8*)(vd + row * 72 + tc8) = vr[j];
            }
        }
        __syncthreads();
    }

    // epilogue: normalize, store bf16 xb[s][h*64+d]
#pragma unroll
    for (int rf = 0; rf < 2; ++rf) {
        float inv[4];
#pragma unroll
        for (int r = 0; r < 4; ++r) inv[r] = 1.0f / l_run[rf][r];
#pragma unroll
        for (int db = 0; db < 4; ++db)
#pragma unroll
            for (int r = 0; r < 4; ++r) {
                int row = s0 + rf * 16 + quad * 4 + r;
                xb[row * NE + h * DH + db * 16 + l15] = (bf16_t)(o_acc[rf][db][r] * inv[r]);
            }
    }
}

// ---------------------------------------------------------------------------
// Projection: Y[4096][1024] = X(bf16) @ W^T(bf16), fp32 out.
// Per wave 32 rows x 64 cols (B-frags reused across 2 row-frags). grid (32,16).
// ---------------------------------------------------------------------------
__global__ __launch_bounds__(256) void proj(const bf16_t* __restrict__ xb,
                                            const bf16_t* __restrict__ wb,
                                            float* __restrict__ y) {
    const int wave = threadIdx.x >> 6;
    const int lane = threadIdx.x & 63;
    const int l15  = lane & 15;
    const int quad = lane >> 4;
    const int m0 = blockIdx.x * 128 + wave * 32;
    const int n0 = blockIdx.y * 64;

    f32x4 acc[2][4];
#pragma unroll
    for (int rf = 0; rf < 2; ++rf)
#pragma unroll
        for (int nb = 0; nb < 4; ++nb) acc[rf][nb] = (f32x4){0.f, 0.f, 0.f, 0.f};

#pragma unroll 2
    for (int k0 = 0; k0 < NE; k0 += 32) {
        bf16x8 a0 = *(const bf16x8*)(xb + (m0 + l15) * NE + k0 + quad * 8);
        bf16x8 a1 = *(const bf16x8*)(xb + (m0 + 16 + l15) * NE + k0 + quad * 8);
#pragma unroll
        for (int nb = 0; nb < 4; ++nb) {
            bf16x8 b = *(const bf16x8*)(wb + (n0 + nb * 16 + l15) * NE + k0 + quad * 8);
            acc[0][nb] = __builtin_amdgcn_mfma_f32_16x16x32_bf16(a0, b, acc[0][nb], 0, 0, 0);
            acc[1][nb] = __builtin_amdgcn_mfma_f32_16x16x32_bf16(a1, b, acc[1][nb], 0, 0, 0);
        }
    }
#pragma unroll
    for (int rf = 0; rf < 2; ++rf)
#pragma unroll
        for (int nb = 0; nb < 4; ++nb)
#pragma unroll
            for (int r = 0; r < 4; ++r)
                y[(m0 + rf * 16 + quad * 4 + r) * NE + n0 + nb * 16 + l15] = acc[rf][nb][r];
}

extern "C" void kernel_launch(void* const* d_in, const int* in_sizes, int n_in,
                              void* d_out, int out_size, void* d_ws, size_t ws_size,
                              hipStream_t stream) {
    const float* q = (const float*)d_in[0];
    const float* k = (const float*)d_in[1];
    const float* v = (const float*)d_in[2];
    const float* w = (const float*)d_in[3];
    float* y = (float*)d_out;

    bf16_t* ws = (bf16_t*)d_ws;
    bf16_t* qb = ws;
    bf16_t* kb = qb + 4 * 1024 * 1024;
    bf16_t* vt = kb + 4 * 1024 * 1024;
    bf16_t* wb = vt + 4 * 1024 * 1024;
    bf16_t* xb = wb + 1024 * 1024;

    pack_qkw<<<dim3(4096), dim3(256), 0, stream>>>(q, k, w, qb, kb, wb);
    pack_vt<<<dim3(S_LEN / 64, NH), dim3(256), 0, stream>>>(v, vt);
    attn<<<dim3(32, NH), dim3(256), 0, stream>>>(qb, kb, vt, xb);
    proj<<<dim3(S_LEN / 128, NE / 64), dim3(256), 0, stream>>>(xb, wb, y);
}